// Round 18
// baseline (142.887 us; speedup 1.0000x reference)
//
#include <hip/hip_runtime.h>
#include <hip/hip_bf16.h>

#define NB 2048
#define NE 4096
#define HID 128
#define NHEAD 8
#define HD 16

// 0.25 * log2(e): scores computed in log2 domain, p = exp2(s)
#define QSCALE 0.36067376022224085f

typedef short s16x8 __attribute__((ext_vector_type(8)));   // 8 bf16
typedef float f32x4  __attribute__((ext_vector_type(4)));
typedef float f32x16 __attribute__((ext_vector_type(16)));

// float -> bf16 (RNE)
static __device__ __forceinline__ ushort f2bf(float x) {
    uint u = __builtin_bit_cast(uint, x);
    uint r = (u + 0x7fffu + ((u >> 16) & 1u)) >> 16;
    return (ushort)r;
}
static __device__ __forceinline__ uint pack2bf(float a, float b) {
    return (uint)f2bf(a) | ((uint)f2bf(b) << 16);
}
// fast pack: round-half-up + byte-perm (3 VALU ops for 2 elements)
static __device__ __forceinline__ uint packrd(float a, float b) {
    uint ua = __builtin_bit_cast(uint, a) + 0x8000u;
    uint ub = __builtin_bit_cast(uint, b) + 0x8000u;
    return __builtin_amdgcn_perm(ub, ua, 0x07060302u);
}

// ---------------------------------------------------------------------------
// Kernel 0: convert + transpose weights to bf16 (coalesced float4 reads,
// scattered 2B writes).
// wb (ushort elems): We1T[128][256] @0, then We2T/WqT/WkT/WvT/WoT [128][128]
// at 32768 + m*16384.  Grid: 112 blocks x 256 thr (28672 threads).
// ---------------------------------------------------------------------------
__global__ __launch_bounds__(256) void convert_kernel(
    const float* __restrict__ We1, const float* __restrict__ We2,
    const float* __restrict__ Wq,  const float* __restrict__ Wk,
    const float* __restrict__ Wv,  const float* __restrict__ Wo,
    ushort* __restrict__ wb)
{
    int i = blockIdx.x * 256 + threadIdx.x;
    if (i < 8192) {                                   // We1T: [n][k=256]
        int k = i >> 5, n4 = (i & 31) * 4;
        float4 t = *(const float4*)(We1 + k * HID + n4);
        wb[(n4 + 0) * 256 + k] = f2bf(t.x);
        wb[(n4 + 1) * 256 + k] = f2bf(t.y);
        wb[(n4 + 2) * 256 + k] = f2bf(t.z);
        wb[(n4 + 3) * 256 + k] = f2bf(t.w);
    } else if (i < 28672) {                           // 5 x [128][128]
        int j = i - 8192;
        int m = j >> 12;                              // 0..4
        int r = j & 4095;
        int k = r >> 5, n4 = (r & 31) * 4;
        const float* W = (m == 0) ? We2 : (m == 1) ? Wq : (m == 2) ? Wk
                       : (m == 3) ? Wv : Wo;
        float4 t = *(const float4*)(W + k * HID + n4);
        ushort* o = wb + 32768 + m * 16384;
        o[(n4 + 0) * 128 + k] = f2bf(t.x);
        o[(n4 + 1) * 128 + k] = f2bf(t.y);
        o[(n4 + 2) * 128 + k] = f2bf(t.z);
        o[(n4 + 3) * 128 + k] = f2bf(t.w);
    }
}

// ---------------------------------------------------------------------------
// Kernel 1: gather -> MLP(256->128 ReLU, 128->128) -> Q,K,V.
// Also initializes d_out = block_features (scatter target; re-done per call).
// 512 threads = 8 waves per block, 16 edges; wave w owns output tile j=w
// (== head w). Grid = 256 blocks. All 24 B-fragments + biases preloaded.
// Outputs: q (pre-scaled by 0.25*log2e), k: bf16 [8][4096][16]; vT [8][16][4096].
// ---------------------------------------------------------------------------
__global__ __launch_bounds__(512, 2) void mlp_qkv_kernel(
    const float* __restrict__ bf, const int* __restrict__ src, const int* __restrict__ dst,
    const ushort* __restrict__ wb,
    const float* __restrict__ be1, const float* __restrict__ be2,
    const float* __restrict__ bq,  const float* __restrict__ bk, const float* __restrict__ bv,
    ushort* __restrict__ qg, ushort* __restrict__ kg, ushort* __restrict__ vT,
    float4* __restrict__ out_init)
{
    __shared__ ushort sX[16][264];   // concat input bf16
    __shared__ ushort sH[16][136];   // hidden (ReLU)
    __shared__ ushort sE[16][136];   // ef

    const int tid = threadIdx.x;
    const int w   = tid >> 6;        // 0..7: output j-tile / head
    const int l   = tid & 63;
    const int lo16 = l & 15;
    const int hi4  = l >> 4;
    const int e0 = blockIdx.x * 16;

    // ---- out = block_features (1 float4/thread for tid<256) ----------------
    if (tid < 256)
        out_init[blockIdx.x * 256 + tid] = ((const float4*)bf)[blockIdx.x * 256 + tid];

    const ushort* We1T = wb;
    const ushort* We2T = wb + 32768;
    const ushort* WqT  = wb + 49152;
    const ushort* WkT  = wb + 65536;
    const ushort* WvT  = wb + 81920;

    // ---- preload: all B-fragments for this wave's j-tile -------------------
    s16x8 B1[8], B2[4], BQ[4], BK[4], BV[4];
    #pragma unroll
    for (int k0 = 0; k0 < 8; k0++)
        B1[k0] = *(const s16x8*)(We1T + (w * 16 + lo16) * 256 + k0 * 32 + hi4 * 8);
    #pragma unroll
    for (int k0 = 0; k0 < 4; k0++) {
        B2[k0] = *(const s16x8*)(We2T + (w * 16 + lo16) * 128 + k0 * 32 + hi4 * 8);
        BQ[k0] = *(const s16x8*)(WqT  + (w * 16 + lo16) * 128 + k0 * 32 + hi4 * 8);
        BK[k0] = *(const s16x8*)(WkT  + (w * 16 + lo16) * 128 + k0 * 32 + hi4 * 8);
        BV[k0] = *(const s16x8*)(WvT  + (w * 16 + lo16) * 128 + k0 * 32 + hi4 * 8);
    }
    const float bias1 = be1[w * 16 + lo16];
    const float bias2 = be2[w * 16 + lo16];
    const float biasq = bq[w * 16 + lo16];
    const float biask = bk[w * 16 + lo16];
    const float biasv = bv[w * 16 + lo16];

    // ---- gather: 16 edges x concat(256) fp32 -> bf16 LDS (8 f/thr) ---------
    {
        const int r  = tid >> 5;          // 0..15 edge
        const int sg = tid & 31;          // 8-float segment
        const int e  = e0 + r;
        const int node = (sg < 16) ? src[e] : dst[e];
        const float4* rowp = (const float4*)(bf + node * HID);
        const int fb = (sg & 15) * 2;
        float4 t0 = rowp[fb], t1 = rowp[fb + 1];
        *(uint2*)&sX[r][sg * 8]     = make_uint2(pack2bf(t0.x, t0.y), pack2bf(t0.z, t0.w));
        *(uint2*)&sX[r][sg * 8 + 4] = make_uint2(pack2bf(t1.x, t1.y), pack2bf(t1.z, t1.w));
    }
    __syncthreads();

    f32x4 acc;

    // ---- GEMM1: hidden = relu(X[16,256] @ We1 + be1) -----------------------
    {
        acc = (f32x4){bias1, bias1, bias1, bias1};
        #pragma unroll
        for (int k0 = 0; k0 < 8; k0++) {
            s16x8 a = *(const s16x8*)&sX[lo16][k0 * 32 + hi4 * 8];
            acc = __builtin_amdgcn_mfma_f32_16x16x32_bf16(a, B1[k0], acc, 0, 0, 0);
        }
        #pragma unroll
        for (int r = 0; r < 4; r++)
            sH[hi4 * 4 + r][w * 16 + lo16] = f2bf(fmaxf(acc[r], 0.0f));
    }
    __syncthreads();

    // ---- GEMM2: ef = H[16,128] @ We2 + be2 ---------------------------------
    {
        acc = (f32x4){bias2, bias2, bias2, bias2};
        #pragma unroll
        for (int k0 = 0; k0 < 4; k0++) {
            s16x8 a = *(const s16x8*)&sH[lo16][k0 * 32 + hi4 * 8];
            acc = __builtin_amdgcn_mfma_f32_16x16x32_bf16(a, B2[k0], acc, 0, 0, 0);
        }
        #pragma unroll
        for (int r = 0; r < 4; r++)
            sE[hi4 * 4 + r][w * 16 + lo16] = f2bf(acc[r]);
    }
    __syncthreads();

    // ---- Q / K / V projections: wave w == head w ---------------------------
#define PROJ(BARR, BIAS, STORE) do { \
    acc = (f32x4){BIAS, BIAS, BIAS, BIAS}; \
    _Pragma("unroll") \
    for (int k0 = 0; k0 < 4; k0++) { \
        s16x8 a = *(const s16x8*)&sE[lo16][k0 * 32 + hi4 * 8]; \
        acc = __builtin_amdgcn_mfma_f32_16x16x32_bf16(a, BARR[k0], acc, 0, 0, 0); \
    } \
    _Pragma("unroll") \
    for (int r = 0; r < 4; r++) { STORE; } \
} while (0)

    PROJ(BQ, biasq, { int e = e0 + hi4 * 4 + r;
                      qg[(w * NE + e) * 16 + lo16] = f2bf(acc[r] * QSCALE); });
    PROJ(BK, biask, { int e = e0 + hi4 * 4 + r;
                      kg[(w * NE + e) * 16 + lo16] = f2bf(acc[r]); });
    PROJ(BV, biasv, { int e = e0 + hi4 * 4 + r;
                      vT[(w * 16 + lo16) * NE + e] = f2bf(acc[r]); });
#undef PROJ
}

// ---------------------------------------------------------------------------
// Kernel 2: attention, 64 q-rows per block / 16 waves (1024 thr).
// Wave w handles keys [w*256,(w+1)*256): 16-way key split (no-max softmax:
// additive), 8 iterations. One K fragment feeds TWO swapped QK^T mfma_32x32x16
// (q-cols 0..31, 32..63); p = exp2(s); L on VALU; P -> bf16 perm-pack ->
// per-wave SINGLE-buffered chunk-major LDS [8][64][4] (same-wave DS ops are
// in-order, dbuf unnecessary) -> 4x PV mfma_16x16x32. LDS reused for the
// 16-way merge. Grid (NE/64, 8) = 512 blocks x 16 waves = 8 waves/SIMD;
// halves K/V L2 traffic vs the 32-q version at unchanged occupancy.
// ---------------------------------------------------------------------------
__global__ __launch_bounds__(1024, 8) void attn_kernel(
    const ushort* __restrict__ qg, const ushort* __restrict__ kg,
    const ushort* __restrict__ vT, ushort* __restrict__ Og)
{
    __shared__ ushort Pbuf[16][2304];  // 72 KB: per-wave P [8][64][4] + merge

    const int tid = threadIdx.x;
    const int w   = tid >> 6;          // 0..15: key-split
    const int l   = tid & 63;
    const int h   = blockIdx.y;
    const int q0  = blockIdx.x * 64;
    const int lo16 = l & 15, hi4 = l >> 4;
    const int lo32 = l & 31, hi2 = l >> 5;

    ushort* Pw = &Pbuf[w][0];

    // Q B-frags: lane holds q-rows q0+lo32 and q0+32+lo32, dims hi2*8..+8
    const s16x8 qfA = *(const s16x8*)(qg + (h * NE + q0 + lo32) * 16 + hi2 * 8);
    const s16x8 qfB = *(const s16x8*)(qg + (h * NE + q0 + 32 + lo32) * 16 + hi2 * 8);

    const f32x16 z16 = {};
    f32x4 o0 = {0,0,0,0}, o1 = {0,0,0,0}, o2 = {0,0,0,0}, o3 = {0,0,0,0};
    float LA = 0.0f, LB = 0.0f;

    const int kbase = w * (NE / 16);   // 256 keys per wave
    const ushort* kp = kg + (size_t)h * NE * 16;
    const ushort* vp = vT + (size_t)(h * 16 + lo16) * NE;

    #pragma unroll 2
    for (int kt = 0; kt < 8; kt++) {
        const int key0 = kbase + kt * 32;
        s16x8 kc = *(const s16x8*)(kp + (key0 + lo32) * 16 + hi2 * 8);
        s16x8 vc = *(const s16x8*)(vp + key0 + hi4 * 8);

        // ---- q-half A (cols 0..31) ----
        {
            f32x16 s = __builtin_amdgcn_mfma_f32_32x32x16_bf16(kc, qfA, z16, 0, 0, 0);
            float e[16];
            #pragma unroll
            for (int i = 0; i < 16; i++) { e[i] = __builtin_amdgcn_exp2f(s[i]); LA += e[i]; }
            #pragma unroll
            for (int g = 0; g < 4; g++) {
                uint2 w2 = make_uint2(packrd(e[4*g], e[4*g+1]), packrd(e[4*g+2], e[4*g+3]));
                *(uint2*)&Pw[((2*g + hi2) * 64 + lo32) * 4] = w2;
            }
        }
        // ---- q-half B (cols 32..63) ----
        {
            f32x16 s = __builtin_amdgcn_mfma_f32_32x32x16_bf16(kc, qfB, z16, 0, 0, 0);
            float e[16];
            #pragma unroll
            for (int i = 0; i < 16; i++) { e[i] = __builtin_amdgcn_exp2f(s[i]); LB += e[i]; }
            #pragma unroll
            for (int g = 0; g < 4; g++) {
                uint2 w2 = make_uint2(packrd(e[4*g], e[4*g+1]), packrd(e[4*g+2], e[4*g+3]));
                *(uint2*)&Pw[((2*g + hi2) * 64 + 32 + lo32) * 4] = w2;
            }
        }

        // ---- PV: 4 q-column groups; keys hi4*8..+8 = chunks 2*hi4, 2*hi4+1 --
        #define PVQ(oX, qc) do { \
            uint2 plo = *(const uint2*)&Pw[((2*hi4)     * 64 + (qc)) * 4]; \
            uint2 phi = *(const uint2*)&Pw[((2*hi4 + 1) * 64 + (qc)) * 4]; \
            s16x8 pb = __builtin_bit_cast(s16x8, make_uint4(plo.x, plo.y, phi.x, phi.y)); \
            oX = __builtin_amdgcn_mfma_f32_16x16x32_bf16(vc, pb, oX, 0, 0, 0); \
        } while (0)
        PVQ(o0, lo16);
        PVQ(o1, 16 + lo16);
        PVQ(o2, 32 + lo16);
        PVQ(o3, 48 + lo16);
        #undef PVQ
    }

    // full per-q L for this wave's 256 keys: halves live in lanes l and l^32
    float LfA = LA + __shfl_xor(LA, 32, 64);
    float LfB = LB + __shfl_xor(LB, 32, 64);

    // reuse Pbuf as the merge buffer: sO[16][64][18] floats (72 KB)
    __syncthreads();
    float* sO = (float*)&Pbuf[0][0];
    #pragma unroll
    for (int r = 0; r < 4; r++) {
        sO[(w * 64 + lo16) * 18 + hi4 * 4 + r]      = o0[r];
        sO[(w * 64 + 16 + lo16) * 18 + hi4 * 4 + r] = o1[r];
        sO[(w * 64 + 32 + lo16) * 18 + hi4 * 4 + r] = o2[r];
        sO[(w * 64 + 48 + lo16) * 18 + hi4 * 4 + r] = o3[r];
    }
    if (hi2 == 0) {                    // one writer per q
        sO[(w * 64 + lo32) * 18 + 16]      = LfA;
        sO[(w * 64 + 32 + lo32) * 18 + 16] = LfB;
    }
    __syncthreads();

    // merge the 16 key-split partials: thread -> (q = tid>>4, d = tid&15)
    {
        const int q = tid >> 4;        // 0..63
        const int d = tid & 15;
        float sum = 0.0f, Lq = 0.0f;
        #pragma unroll
        for (int ww = 0; ww < 16; ww++) {
            sum += sO[(ww * 64 + q) * 18 + d];
            Lq  += sO[(ww * 64 + q) * 18 + 16];
        }
        Og[(q0 + q) * HID + h * 16 + d] = f2bf(sum / Lq);
    }
}

// ---------------------------------------------------------------------------
// Kernel 3: updated = O @ Wo + bo (MFMA), float atomic scatter DIRECTLY into
// d_out (pre-initialized to block_features by mlp_qkv).
// 512 threads = 8 waves, 16 edges; wave w owns j-tile w. Grid = 256.
// ---------------------------------------------------------------------------
__global__ __launch_bounds__(512, 2) void wo_scatter_kernel(
    const ushort* __restrict__ Og, const ushort* __restrict__ wb,
    const float* __restrict__ bo, const int* __restrict__ dst,
    float* __restrict__ out)
{
    const int tid = threadIdx.x;
    const int w   = tid >> 6;
    const int l   = tid & 63;
    const int lo16 = l & 15, hi4 = l >> 4;
    const int e0 = blockIdx.x * 16;
    const ushort* WoT = wb + 98304;

    // preload everything
    s16x8 BO[4], AO[4];
    #pragma unroll
    for (int k0 = 0; k0 < 4; k0++) {
        BO[k0] = *(const s16x8*)(WoT + (w * 16 + lo16) * 128 + k0 * 32 + hi4 * 8);
        AO[k0] = *(const s16x8*)(Og + (e0 + lo16) * HID + k0 * 32 + hi4 * 8);
    }
    int dste[4];
    #pragma unroll
    for (int r = 0; r < 4; r++) dste[r] = dst[e0 + hi4 * 4 + r];
    const float b_ = bo[w * 16 + lo16];

    f32x4 acc = (f32x4){b_, b_, b_, b_};
    #pragma unroll
    for (int k0 = 0; k0 < 4; k0++)
        acc = __builtin_amdgcn_mfma_f32_16x16x32_bf16(AO[k0], BO[k0], acc, 0, 0, 0);

    #pragma unroll
    for (int r = 0; r < 4; r++) {
        atomicAdd(out + dste[r] * HID + w * 16 + lo16, acc[r]);
    }
}

// ---------------------------------------------------------------------------
extern "C" void kernel_launch(void* const* d_in, const int* in_sizes, int n_in,
                              void* d_out, int out_size, void* d_ws, size_t ws_size,
                              hipStream_t stream)
{
    const float* bf  = (const float*)d_in[0];
    const int*   ei  = (const int*)d_in[1];
    const int*   src = ei;
    const int*   dst = ei + NE;
    const float* We1 = (const float*)d_in[2];
    const float* be1 = (const float*)d_in[3];
    const float* We2 = (const float*)d_in[4];
    const float* be2 = (const float*)d_in[5];
    const float* Wq  = (const float*)d_in[6];
    const float* bq  = (const float*)d_in[7];
    const float* Wk  = (const float*)d_in[8];
    const float* bk  = (const float*)d_in[9];
    const float* Wv  = (const float*)d_in[10];
    const float* bv  = (const float*)d_in[11];
    const float* Wo  = (const float*)d_in[12];
    const float* bo  = (const float*)d_in[13];

    char* ws = (char*)d_ws;
    ushort* wb  = (ushort*)(ws);                      // 229376 B
    ushort* qg  = (ushort*)(ws + (1u<<18));           // [8][4096][16] bf16, 1 MB
    ushort* kg  = (ushort*)(ws + (1u<<18) + (1u<<20));
    ushort* vT  = (ushort*)(ws + (1u<<18) + (2u<<20));  // [8][16][4096] bf16, 1 MB
    ushort* Og  = (ushort*)(ws + (1u<<18) + (3u<<20));  // [4096][128] bf16, 1 MB

    convert_kernel<<<112, 256, 0, stream>>>(We1, We2, Wq, Wk, Wv, Wo, wb);
    mlp_qkv_kernel<<<NE / 16, 512, 0, stream>>>(bf, src, dst, wb, be1, be2, bq, bk, bv,
                                                qg, kg, vT, (float4*)d_out);
    attn_kernel<<<dim3(NE / 64, NHEAD), 1024, 0, stream>>>(qg, kg, vT, Og);
    wo_scatter_kernel<<<NE / 16, 512, 0, stream>>>(Og, wb, bo, dst, (float*)d_out);
}

// Round 19
// 47.823 us; speedup vs baseline: 2.9878x; 2.9878x over previous
//
#include <hip/hip_runtime.h>
#include <hip/hip_bf16.h>

#define NB 2048
#define NE 4096
#define HID 128
#define NHEAD 8
#define HD 16

// 0.25 * log2(e): scores computed in log2 domain, p = exp2(s)
#define QSCALE 0.36067376022224085f

typedef short s16x8 __attribute__((ext_vector_type(8)));   // 8 bf16
typedef float f32x4  __attribute__((ext_vector_type(4)));
typedef float f32x16 __attribute__((ext_vector_type(16)));

// float -> bf16 (RNE)
static __device__ __forceinline__ ushort f2bf(float x) {
    uint u = __builtin_bit_cast(uint, x);
    uint r = (u + 0x7fffu + ((u >> 16) & 1u)) >> 16;
    return (ushort)r;
}
static __device__ __forceinline__ uint pack2bf(float a, float b) {
    return (uint)f2bf(a) | ((uint)f2bf(b) << 16);
}
// fast pack: round-half-up + byte-perm (3 VALU ops for 2 elements)
static __device__ __forceinline__ uint packrd(float a, float b) {
    uint ua = __builtin_bit_cast(uint, a) + 0x8000u;
    uint ub = __builtin_bit_cast(uint, b) + 0x8000u;
    return __builtin_amdgcn_perm(ub, ua, 0x07060302u);
}

// ---------------------------------------------------------------------------
// Kernel 0: convert + transpose weights to bf16 (coalesced float4 reads,
// scattered 2B writes).
// wb (ushort elems): We1T[128][256] @0, then We2T/WqT/WkT/WvT/WoT [128][128]
// at 32768 + m*16384.  Grid: 112 blocks x 256 thr (28672 threads).
// ---------------------------------------------------------------------------
__global__ __launch_bounds__(256) void convert_kernel(
    const float* __restrict__ We1, const float* __restrict__ We2,
    const float* __restrict__ Wq,  const float* __restrict__ Wk,
    const float* __restrict__ Wv,  const float* __restrict__ Wo,
    ushort* __restrict__ wb)
{
    int i = blockIdx.x * 256 + threadIdx.x;
    if (i < 8192) {                                   // We1T: [n][k=256]
        int k = i >> 5, n4 = (i & 31) * 4;
        float4 t = *(const float4*)(We1 + k * HID + n4);
        wb[(n4 + 0) * 256 + k] = f2bf(t.x);
        wb[(n4 + 1) * 256 + k] = f2bf(t.y);
        wb[(n4 + 2) * 256 + k] = f2bf(t.z);
        wb[(n4 + 3) * 256 + k] = f2bf(t.w);
    } else if (i < 28672) {                           // 5 x [128][128]
        int j = i - 8192;
        int m = j >> 12;                              // 0..4
        int r = j & 4095;
        int k = r >> 5, n4 = (r & 31) * 4;
        const float* W = (m == 0) ? We2 : (m == 1) ? Wq : (m == 2) ? Wk
                       : (m == 3) ? Wv : Wo;
        float4 t = *(const float4*)(W + k * HID + n4);
        ushort* o = wb + 32768 + m * 16384;
        o[(n4 + 0) * 128 + k] = f2bf(t.x);
        o[(n4 + 1) * 128 + k] = f2bf(t.y);
        o[(n4 + 2) * 128 + k] = f2bf(t.z);
        o[(n4 + 3) * 128 + k] = f2bf(t.w);
    }
}

// ---------------------------------------------------------------------------
// Kernel 1: gather -> MLP(256->128 ReLU, 128->128) -> Q,K,V.
// Also initializes d_out = block_features (scatter target; re-done per call).
// 512 threads = 8 waves per block, 16 edges; wave w owns output tile j=w
// (== head w). Grid = 256 blocks. All 24 B-fragments + biases preloaded.
// Outputs: q (pre-scaled by 0.25*log2e), k: bf16 [8][4096][16]; vT [8][16][4096].
// ---------------------------------------------------------------------------
__global__ __launch_bounds__(512, 2) void mlp_qkv_kernel(
    const float* __restrict__ bf, const int* __restrict__ src, const int* __restrict__ dst,
    const ushort* __restrict__ wb,
    const float* __restrict__ be1, const float* __restrict__ be2,
    const float* __restrict__ bq,  const float* __restrict__ bk, const float* __restrict__ bv,
    ushort* __restrict__ qg, ushort* __restrict__ kg, ushort* __restrict__ vT,
    float4* __restrict__ out_init)
{
    __shared__ ushort sX[16][264];   // concat input bf16
    __shared__ ushort sH[16][136];   // hidden (ReLU)
    __shared__ ushort sE[16][136];   // ef

    const int tid = threadIdx.x;
    const int w   = tid >> 6;        // 0..7: output j-tile / head
    const int l   = tid & 63;
    const int lo16 = l & 15;
    const int hi4  = l >> 4;
    const int e0 = blockIdx.x * 16;

    // ---- out = block_features (1 float4/thread for tid<256) ----------------
    if (tid < 256)
        out_init[blockIdx.x * 256 + tid] = ((const float4*)bf)[blockIdx.x * 256 + tid];

    const ushort* We1T = wb;
    const ushort* We2T = wb + 32768;
    const ushort* WqT  = wb + 49152;
    const ushort* WkT  = wb + 65536;
    const ushort* WvT  = wb + 81920;

    // ---- preload: all B-fragments for this wave's j-tile -------------------
    s16x8 B1[8], B2[4], BQ[4], BK[4], BV[4];
    #pragma unroll
    for (int k0 = 0; k0 < 8; k0++)
        B1[k0] = *(const s16x8*)(We1T + (w * 16 + lo16) * 256 + k0 * 32 + hi4 * 8);
    #pragma unroll
    for (int k0 = 0; k0 < 4; k0++) {
        B2[k0] = *(const s16x8*)(We2T + (w * 16 + lo16) * 128 + k0 * 32 + hi4 * 8);
        BQ[k0] = *(const s16x8*)(WqT  + (w * 16 + lo16) * 128 + k0 * 32 + hi4 * 8);
        BK[k0] = *(const s16x8*)(WkT  + (w * 16 + lo16) * 128 + k0 * 32 + hi4 * 8);
        BV[k0] = *(const s16x8*)(WvT  + (w * 16 + lo16) * 128 + k0 * 32 + hi4 * 8);
    }
    const float bias1 = be1[w * 16 + lo16];
    const float bias2 = be2[w * 16 + lo16];
    const float biasq = bq[w * 16 + lo16];
    const float biask = bk[w * 16 + lo16];
    const float biasv = bv[w * 16 + lo16];

    // ---- gather: 16 edges x concat(256) fp32 -> bf16 LDS (8 f/thr) ---------
    {
        const int r  = tid >> 5;          // 0..15 edge
        const int sg = tid & 31;          // 8-float segment
        const int e  = e0 + r;
        const int node = (sg < 16) ? src[e] : dst[e];
        const float4* rowp = (const float4*)(bf + node * HID);
        const int fb = (sg & 15) * 2;
        float4 t0 = rowp[fb], t1 = rowp[fb + 1];
        *(uint2*)&sX[r][sg * 8]     = make_uint2(pack2bf(t0.x, t0.y), pack2bf(t0.z, t0.w));
        *(uint2*)&sX[r][sg * 8 + 4] = make_uint2(pack2bf(t1.x, t1.y), pack2bf(t1.z, t1.w));
    }
    __syncthreads();

    f32x4 acc;

    // ---- GEMM1: hidden = relu(X[16,256] @ We1 + be1) -----------------------
    {
        acc = (f32x4){bias1, bias1, bias1, bias1};
        #pragma unroll
        for (int k0 = 0; k0 < 8; k0++) {
            s16x8 a = *(const s16x8*)&sX[lo16][k0 * 32 + hi4 * 8];
            acc = __builtin_amdgcn_mfma_f32_16x16x32_bf16(a, B1[k0], acc, 0, 0, 0);
        }
        #pragma unroll
        for (int r = 0; r < 4; r++)
            sH[hi4 * 4 + r][w * 16 + lo16] = f2bf(fmaxf(acc[r], 0.0f));
    }
    __syncthreads();

    // ---- GEMM2: ef = H[16,128] @ We2 + be2 ---------------------------------
    {
        acc = (f32x4){bias2, bias2, bias2, bias2};
        #pragma unroll
        for (int k0 = 0; k0 < 4; k0++) {
            s16x8 a = *(const s16x8*)&sH[lo16][k0 * 32 + hi4 * 8];
            acc = __builtin_amdgcn_mfma_f32_16x16x32_bf16(a, B2[k0], acc, 0, 0, 0);
        }
        #pragma unroll
        for (int r = 0; r < 4; r++)
            sE[hi4 * 4 + r][w * 16 + lo16] = f2bf(acc[r]);
    }
    __syncthreads();

    // ---- Q / K / V projections: wave w == head w ---------------------------
#define PROJ(BARR, BIAS, STORE) do { \
    acc = (f32x4){BIAS, BIAS, BIAS, BIAS}; \
    _Pragma("unroll") \
    for (int k0 = 0; k0 < 4; k0++) { \
        s16x8 a = *(const s16x8*)&sE[lo16][k0 * 32 + hi4 * 8]; \
        acc = __builtin_amdgcn_mfma_f32_16x16x32_bf16(a, BARR[k0], acc, 0, 0, 0); \
    } \
    _Pragma("unroll") \
    for (int r = 0; r < 4; r++) { STORE; } \
} while (0)

    PROJ(BQ, biasq, { int e = e0 + hi4 * 4 + r;
                      qg[(w * NE + e) * 16 + lo16] = f2bf(acc[r] * QSCALE); });
    PROJ(BK, biask, { int e = e0 + hi4 * 4 + r;
                      kg[(w * NE + e) * 16 + lo16] = f2bf(acc[r]); });
    PROJ(BV, biasv, { int e = e0 + hi4 * 4 + r;
                      vT[(w * 16 + lo16) * NE + e] = f2bf(acc[r]); });
#undef PROJ
}

// ---------------------------------------------------------------------------
// Kernel 2: attention (best verified structure). 512 thr = 8 waves,
// 32 q-rows of one head; wave w handles keys [w*512,(w+1)*512) (no-max
// softmax: additive). Swapped QK^T (mfma_32x32x16 -> S^T, lane owns one
// q-row); p = exp2(s); L on VALU; P -> bf16 perm-pack -> per-wave chunk-major
// LDS (conflict-free b64) -> PV mfma_16x16x32. LDS reused for the 8-way merge.
// ---------------------------------------------------------------------------
__global__ __launch_bounds__(512, 8) void attn_kernel(
    const ushort* __restrict__ qg, const ushort* __restrict__ kg,
    const ushort* __restrict__ vT, ushort* __restrict__ Og)
{
    __shared__ ushort Pbuf[8][2048];   // 32 KB: per-wave P [2][8][32][4]

    const int tid = threadIdx.x;
    const int w   = tid >> 6;
    const int l   = tid & 63;
    const int h   = blockIdx.y;
    const int q0  = blockIdx.x * 32;
    const int lo16 = l & 15, hi4 = l >> 4;
    const int lo32 = l & 31, hi2 = l >> 5;

    ushort* Pw = &Pbuf[w][0];

    // Q B-frag: lane holds q-row q0+lo32, dims hi2*8..+8 (held across loop)
    const s16x8 qf = *(const s16x8*)(qg + (h * NE + q0 + lo32) * 16 + hi2 * 8);

    const f32x16 z16 = {};
    f32x4 o0 = {0,0,0,0}, o1 = {0,0,0,0};
    float L = 0.0f;

    const int kbase = w * (NE / 8);    // 512 keys per wave
    const ushort* kp = kg + (size_t)h * NE * 16;
    const ushort* vp = vT + (size_t)(h * 16 + lo16) * NE;

    #pragma unroll 2
    for (int kt = 0; kt < 16; kt++) {
        const int key0 = kbase + kt * 32;
        s16x8 kc = *(const s16x8*)(kp + (key0 + lo32) * 16 + hi2 * 8);
        s16x8 vc = *(const s16x8*)(vp + key0 + hi4 * 8);

        f32x16 s = __builtin_amdgcn_mfma_f32_32x32x16_bf16(kc, qf, z16, 0, 0, 0);

        // p = exp2(s); reg r holds key (r&3)+8*(r>>2)+4*hi2, q = lo32.
        float e[16];
        #pragma unroll
        for (int i = 0; i < 16; i++) { e[i] = __builtin_amdgcn_exp2f(s[i]); L += e[i]; }

        const int b8 = (kt & 1) * 8;
        #pragma unroll
        for (int g = 0; g < 4; g++) {
            uint2 w2 = make_uint2(packrd(e[4*g], e[4*g+1]), packrd(e[4*g+2], e[4*g+3]));
            *(uint2*)&Pw[((b8 + 2*g + hi2) * 32 + lo32) * 4] = w2;
        }

        // PV B-frags: q-col lo16 (+16), keys hi4*8..+8 = chunks 2*hi4, 2*hi4+1
        uint2 alo = *(const uint2*)&Pw[((b8 + 2*hi4)     * 32 + lo16) * 4];
        uint2 ahi = *(const uint2*)&Pw[((b8 + 2*hi4 + 1) * 32 + lo16) * 4];
        uint2 blo = *(const uint2*)&Pw[((b8 + 2*hi4)     * 32 + 16 + lo16) * 4];
        uint2 bhi = *(const uint2*)&Pw[((b8 + 2*hi4 + 1) * 32 + 16 + lo16) * 4];
        s16x8 pb0 = __builtin_bit_cast(s16x8, make_uint4(alo.x, alo.y, ahi.x, ahi.y));
        s16x8 pb1 = __builtin_bit_cast(s16x8, make_uint4(blo.x, blo.y, bhi.x, bhi.y));

        o0 = __builtin_amdgcn_mfma_f32_16x16x32_bf16(vc, pb0, o0, 0, 0, 0);
        o1 = __builtin_amdgcn_mfma_f32_16x16x32_bf16(vc, pb1, o1, 0, 0, 0);
    }

    // full per-q L for this wave's 512 keys: halves live in lanes l and l^32
    float Lf = L + __shfl_xor(L, 32, 64);

    // reuse Pbuf as the merge buffer: sO[8][32][18] floats (18.4 KB < 32 KB)
    __syncthreads();
    float* sO = (float*)&Pbuf[0][0];
    #pragma unroll
    for (int r = 0; r < 4; r++) {
        sO[(w * 32 + lo16) * 18 + hi4 * 4 + r]      = o0[r];
        sO[(w * 32 + 16 + lo16) * 18 + hi4 * 4 + r] = o1[r];
    }
    if (hi2 == 0) sO[(w * 32 + lo32) * 18 + 16] = Lf;   // one writer per q
    __syncthreads();

    // merge the 8 key-split partials: thread -> (q = tid>>4, d = tid&15)
    {
        const int q = tid >> 4;
        const int d = tid & 15;
        float sum = 0.0f, Lq = 0.0f;
        #pragma unroll
        for (int ww = 0; ww < 8; ww++) {
            sum += sO[(ww * 32 + q) * 18 + d];
            Lq  += sO[(ww * 32 + q) * 18 + 16];
        }
        Og[(q0 + q) * HID + h * 16 + d] = f2bf(sum / Lq);
    }
}

// ---------------------------------------------------------------------------
// Kernel 3: updated = O @ Wo + bo (MFMA), float atomic scatter DIRECTLY into
// d_out (pre-initialized to block_features by mlp_qkv).
// 512 threads = 8 waves, 16 edges; wave w owns j-tile w. Grid = 256.
// ---------------------------------------------------------------------------
__global__ __launch_bounds__(512, 2) void wo_scatter_kernel(
    const ushort* __restrict__ Og, const ushort* __restrict__ wb,
    const float* __restrict__ bo, const int* __restrict__ dst,
    float* __restrict__ out)
{
    const int tid = threadIdx.x;
    const int w   = tid >> 6;
    const int l   = tid & 63;
    const int lo16 = l & 15, hi4 = l >> 4;
    const int e0 = blockIdx.x * 16;
    const ushort* WoT = wb + 98304;

    // preload everything
    s16x8 BO[4], AO[4];
    #pragma unroll
    for (int k0 = 0; k0 < 4; k0++) {
        BO[k0] = *(const s16x8*)(WoT + (w * 16 + lo16) * 128 + k0 * 32 + hi4 * 8);
        AO[k0] = *(const s16x8*)(Og + (e0 + lo16) * HID + k0 * 32 + hi4 * 8);
    }
    int dste[4];
    #pragma unroll
    for (int r = 0; r < 4; r++) dste[r] = dst[e0 + hi4 * 4 + r];
    const float b_ = bo[w * 16 + lo16];

    f32x4 acc = (f32x4){b_, b_, b_, b_};
    #pragma unroll
    for (int k0 = 0; k0 < 4; k0++)
        acc = __builtin_amdgcn_mfma_f32_16x16x32_bf16(AO[k0], BO[k0], acc, 0, 0, 0);

    #pragma unroll
    for (int r = 0; r < 4; r++) {
        atomicAdd(out + dste[r] * HID + w * 16 + lo16, acc[r]);
    }
}

// ---------------------------------------------------------------------------
extern "C" void kernel_launch(void* const* d_in, const int* in_sizes, int n_in,
                              void* d_out, int out_size, void* d_ws, size_t ws_size,
                              hipStream_t stream)
{
    const float* bf  = (const float*)d_in[0];
    const int*   ei  = (const int*)d_in[1];
    const int*   src = ei;
    const int*   dst = ei + NE;
    const float* We1 = (const float*)d_in[2];
    const float* be1 = (const float*)d_in[3];
    const float* We2 = (const float*)d_in[4];
    const float* be2 = (const float*)d_in[5];
    const float* Wq  = (const float*)d_in[6];
    const float* bq  = (const float*)d_in[7];
    const float* Wk  = (const float*)d_in[8];
    const float* bk  = (const float*)d_in[9];
    const float* Wv  = (const float*)d_in[10];
    const float* bv  = (const float*)d_in[11];
    const float* Wo  = (const float*)d_in[12];
    const float* bo  = (const float*)d_in[13];

    char* ws = (char*)d_ws;
    ushort* wb  = (ushort*)(ws);                      // 229376 B
    ushort* qg  = (ushort*)(ws + (1u<<18));           // [8][4096][16] bf16, 1 MB
    ushort* kg  = (ushort*)(ws + (1u<<18) + (1u<<20));
    ushort* vT  = (ushort*)(ws + (1u<<18) + (2u<<20));  // [8][16][4096] bf16, 1 MB
    ushort* Og  = (ushort*)(ws + (1u<<18) + (3u<<20));  // [4096][128] bf16, 1 MB

    convert_kernel<<<112, 256, 0, stream>>>(We1, We2, Wq, Wk, Wv, Wo, wb);
    mlp_qkv_kernel<<<NE / 16, 512, 0, stream>>>(bf, src, dst, wb, be1, be2, bq, bk, bv,
                                                qg, kg, vT, (float4*)d_out);
    attn_kernel<<<dim3(NE / 32, NHEAD), 512, 0, stream>>>(qg, kg, vT, Og);
    wo_scatter_kernel<<<NE / 16, 512, 0, stream>>>(Og, wb, bo, dst, (float*)d_out);
}